// Round 13
// baseline (218.215 us; speedup 1.0000x reference)
//
#include <hip/hip_runtime.h>
#include <stdint.h>

typedef unsigned short u16;
typedef unsigned int   u32;

typedef __bf16 bf16x8 __attribute__((ext_vector_type(8)));
typedef float  fx4    __attribute__((ext_vector_type(4)));
typedef u16    u16x8  __attribute__((ext_vector_type(8)));
typedef u16    u16x4  __attribute__((ext_vector_type(4)));

typedef __attribute__((address_space(1))) unsigned int as1_u32;
typedef __attribute__((address_space(3))) unsigned int as3_u32;

// async global->LDS, 16B per lane. LDS dest is wave-uniform base + lane*16.
__device__ __forceinline__ void gload_lds16(const void* g, void* lds) {
  __builtin_amdgcn_global_load_lds((const as1_u32*)(uintptr_t)g,
                                   (as3_u32*)(uintptr_t)lds, 16, 0, 0);
}

__device__ __forceinline__ float b2f(u32 bits) {
  union { u32 i; float f; } v; v.i = bits << 16; return v.f;
}
__device__ __forceinline__ u16 f2b(float f) {
  union { float f; u32 i; } v; v.f = f;
  u32 x = v.i;
  return (u16)((x + 0x7fffu + ((x >> 16) & 1u)) >> 16);  // RNE (sw)
}
// hardware bf16 convert (compiler lowers to native cvt on gfx950).
__device__ __forceinline__ u16 f2b_hw(float f) {
  union { __bf16 b; u16 u; } v; v.b = (__bf16)f; return v.u;
}
// raw v_exp_f32: computes 2^x. (__exp2f collides with glibc math.h -- r8.)
__device__ __forceinline__ float exp2_hw(float f) {
  return __builtin_amdgcn_exp2f(f);
}
// packed f32x2 -> bf16x2 convert: dst.lo = cvt(a), dst.hi = cvt(b).
__device__ __forceinline__ u32 cvtpk_bf16(float a, float b) {
  u32 r;
  asm("v_cvt_pk_bf16_f32 %0, %1, %2" : "=v"(r) : "v"(a), "v"(b));
  return r;
}

// ---------------------------------------------------------------------------
// Cast f32 -> bf16 for x, Wq, Wk, Wv, Wo into contiguous ws regions.
// ---------------------------------------------------------------------------
__global__ __launch_bounds__(256) void cast_kernel(
    const float* __restrict__ s0, const float* __restrict__ s1,
    const float* __restrict__ s2, const float* __restrict__ s3,
    const float* __restrict__ s4, u16* __restrict__ dst)
{
  const size_t i8 = ((size_t)blockIdx.x * 256 + threadIdx.x) * 8;
  if (i8 >= 14680064) return;
  const float* src; size_t off;
  if      (i8 <  4194304) { src = s0; off = i8; }
  else if (i8 <  8388608) { src = s1; off = i8 - 4194304; }
  else if (i8 <  9437184) { src = s2; off = i8 - 8388608; }
  else if (i8 < 10485760) { src = s3; off = i8 - 9437184; }
  else                    { src = s4; off = i8 - 10485760; }
  const float4 a = *(const float4*)(src + off);
  const float4 b = *(const float4*)(src + off + 4);
  u16x8 o;
  o[0] = f2b(a.x); o[1] = f2b(a.y); o[2] = f2b(a.z); o[3] = f2b(a.w);
  o[4] = f2b(b.x); o[5] = f2b(b.y); o[6] = f2b(b.z); o[7] = f2b(b.w);
  *(u16x8*)(dst + i8) = o;
}

// ---------------------------------------------------------------------------
// bf16 MFMA GEMM: C[M,N] = A[M,K] * B[N,K]^T, fp32 accum.
// r9/r12-proven config (44 us QKV, conflicts 0; at the measured 2-phase
// structure ceiling ~607 TF, m233): 8 waves / 512 threads, wave-tile 32x64,
// 128x128 block tile, BK=32, 5-buffer 4-ahead async gload_lds pipeline
// (80KB LDS, 2 blk/CU), exact vmcnt ladder 6/4/2/0, LDS XOR swizzle.
// Q pre-scale folds 1/sqrt(D) * log2(e) so attn uses bare v_exp_f32 (=2^x).
// MODE 0: QKV epilogue -- RoPE fused on f32 acc for Q and K; V cols stored
//         TRANSPOSED directly to vt.
// MODE 1: plain f32 store (output projection).
// ---------------------------------------------------------------------------
template <int MODE>
__global__ __launch_bounds__(512) void gemm_bt(
    const u16* __restrict__ A, const u16* __restrict__ B0,
    const u16* __restrict__ B1, const u16* __restrict__ B2,
    void* __restrict__ Cv, int K, int split1, int split2, int ldc,
    const float* __restrict__ cosb, const float* __restrict__ sinb,
    u16* __restrict__ vtg)
{
  __shared__ __align__(16) u16 smem[5 * 8192];   // 5 bufs x (A 8KB + B 8KB)

  const int n0 = blockIdx.x * 128;
  const int m0 = blockIdx.y * 128;

  const u16* Bsel; int nb;
  if (n0 < split1)      { Bsel = B0; nb = n0; }
  else if (n0 < split2) { Bsel = B1; nb = n0 - split1; }
  else                  { Bsel = B2; nb = n0 - split2; }

  const int tid  = threadIdx.x;
  const int wave = tid >> 6, lane = tid & 63;
  const int wm = wave >> 1, wn = wave & 1;     // wave tile: 32 rows x 64 cols
  const int quad = lane >> 4, l16 = lane & 15;

  fx4 acc[2][4];
#pragma unroll
  for (int i = 0; i < 2; ++i)
#pragma unroll
    for (int j = 0; j < 4; ++j) acc[i][j] = fx4{0.f, 0.f, 0.f, 0.f};

  const int row = tid >> 2;            // 0..127: one 16B chunk per thread
  const int ch  = tid & 3;
  const int csw = (ch ^ ((row >> 1) & 3)) * 8;   // pre-swizzled global chunk
  auto stage = [&](int kt, int buf) {
    u16* As = smem + buf * 8192;
    u16* Bs = As + 4096;
    const int k0 = kt * 32;
    gload_lds16(A    + (size_t)(m0 + row) * K + k0 + csw, As + tid * 8);
    gload_lds16(Bsel + (size_t)(nb + row) * K + k0 + csw, Bs + tid * 8);
  };

  const int KT = K >> 5;               // = 64 for all our shapes
  stage(0, 0); stage(1, 1); stage(2, 2); stage(3, 3);
  int bufR = 0, bufW = 4;              // rotating mod-5 buffer counters

  // frag-read swizzle: f(row) = (row>>1)&3 = (l16>>1)&3 (bases = 0 mod 4)
  const int fx = (l16 >> 1) & 3;
  const int cA = (quad ^ fx) * 8;      // swizzled chunk offset (u16 units)

#pragma unroll 1
  for (int kt = 0; kt < KT; ++kt) {
    const int rem = KT - 1 - kt;       // stages newer than kt still issued
    // stage kt complete; up to 3 newer stages (2 loads/thread each) may fly
    if (rem >= 3)      asm volatile("s_waitcnt vmcnt(6)\n\ts_barrier" ::: "memory");
    else if (rem == 2) asm volatile("s_waitcnt vmcnt(4)\n\ts_barrier" ::: "memory");
    else if (rem == 1) asm volatile("s_waitcnt vmcnt(2)\n\ts_barrier" ::: "memory");
    else               asm volatile("s_waitcnt vmcnt(0)\n\ts_barrier" ::: "memory");
    if (kt + 4 < KT) stage(kt + 4, bufW);  // bufW == buf read at kt-1:
                                           // consumed, all waves past barrier

    const u16* As = smem + bufR * 8192;
    const u16* Bs = As + 4096;

    bf16x8 af[2], bfr[4];
#pragma unroll
    for (int t = 0; t < 2; ++t)
      af[t]  = *(const bf16x8*)&As[(wm * 32 + t * 16 + l16) * 32 + cA];
#pragma unroll
    for (int t = 0; t < 4; ++t)
      bfr[t] = *(const bf16x8*)&Bs[(wn * 64 + t * 16 + l16) * 32 + cA];
#pragma unroll
    for (int ti = 0; ti < 2; ++ti)
#pragma unroll
      for (int tj = 0; tj < 4; ++tj)
        acc[ti][tj] = __builtin_amdgcn_mfma_f32_16x16x32_bf16(
            af[ti], bfr[tj], acc[ti][tj], 0, 0, 0);

    bufR = (bufR == 4) ? 0 : bufR + 1;
    bufW = (bufW == 4) ? 0 : bufW + 1;
  }

  if (MODE == 1) {                     // plain f32 store (out-proj)
    float* C = (float*)Cv;
#pragma unroll
    for (int ti = 0; ti < 2; ++ti) {
      const int row_b = m0 + wm * 32 + ti * 16 + quad * 4;
#pragma unroll
      for (int tj = 0; tj < 4; ++tj) {
        const int col = n0 + wn * 64 + tj * 16 + l16;
#pragma unroll
        for (int r = 0; r < 4; ++r)
          C[(size_t)(row_b + r) * ldc + col] = acc[ti][tj][r];
      }
    }
  } else {                             // QKV epilogue
    u16* C = (u16*)Cv;
    const int cb = n0 + wn * 64;       // wave's 64-col span = one head block
    if (cb < 2560) {                   // Q or K: fuse RoPE
      // Q: 2^-3 (1/sqrt(D)) * log2(e) so attn can use v_exp_f32 (=2^x)
      const float qs = (cb < 2048) ? 0.18033688f : 1.0f;
#pragma unroll
      for (int ti = 0; ti < 2; ++ti) {
#pragma unroll
        for (int r = 0; r < 4; ++r) {
          const int s = m0 + wm * 32 + ti * 16 + quad * 4 + r;
          const float* cr = cosb + s * 64;
          const float* sr = sinb + s * 64;
          u16* orow = C + (size_t)s * 3072 + cb;
#pragma unroll
          for (int tj = 0; tj < 2; ++tj) {
            const int d0 = tj * 16 + l16, d1 = d0 + 32;
            const float x0 = acc[ti][tj][r], x1 = acc[ti][tj + 2][r];
            orow[d0] = f2b((x0 * cr[d0] - x1 * sr[d0]) * qs);
            orow[d1] = f2b((x1 * cr[d1] + x0 * sr[d1]) * qs);
          }
        }
      }
    } else {                           // V: store TRANSPOSED to vt[d][key]
      const int vr0 = cb - 2560;
#pragma unroll
      for (int ti = 0; ti < 2; ++ti) {
        const int s0 = m0 + wm * 32 + ti * 16 + quad * 4;
#pragma unroll
        for (int tj = 0; tj < 4; ++tj) {
          const int vr = vr0 + tj * 16 + l16;
          u16x4 o;
#pragma unroll
          for (int r = 0; r < 4; ++r) o[r] = f2b(acc[ti][tj][r]);
          *(u16x4*)(vtg + (size_t)vr * 2048 + s0) = o;
        }
      }
    }
  }
}

// ---------------------------------------------------------------------------
// MFMA causal flash attention.
// ROUND-23: QBLK 64 -> 128 (32 q-rows/wave). r12 DS arithmetic: all 4 waves
// re-read identical K/V frags; per wave-half 20KB of DS for only 16 q-rows
// (1.25 KB/q, attn LDS floor ~26us of ~40us). Doubling q/wave amortizes the
// K/V reads over 2x output: 22KB per 32 q (0.69 KB/q, floor ~15us).
//  * Q held in REGISTERS (4 frags/wave, hoisted); staged through the Kb
//    buffer before the K/V loop (read->reg, barrier, buffer reused).
//    LDS stays 48KB: K 16 + V 16 + Ps 16.
//  * Grid 512 blocks = exactly 2/CU. qt ordering pairs heavy tile (15-k)
//    with light tile (k) on each CU under round-robin dispatch -> uniform
//    ~34 halves/CU (zero tail).
//  * Per-(wave,group) uniform causal-mask branch (finer than block-level).
// r12 structure otherwise: swapped QK^T (mfma(K,Q) -> lane holds
// P[key][q=l16]), in-register softmax w/ exp2 (log2e folded into Q),
// packed-u32 Ps (cvt_pk + ds_write_b64, pair-chunk swizzle), KV-head-
// localized XCD remap (bi&7=kvh -> per-XCD K+V 512KB L2-resident), async
// gload_lds staging, depth-1 double-buffered 64-key halves, s_setprio.
// ---------------------------------------------------------------------------
__global__ __launch_bounds__(256) void attn_kernel(
    const u16* __restrict__ qkv, const u16* __restrict__ vt,
    u16* __restrict__ attnbuf)
{
  const int bi  = blockIdx.x;
  const int kvh = bi & 7;                  // XCD-local kv head
  const int hs  = (bi >> 3) & 3;
  const int h   = kvh * 4 + hs;            // head
  const int g5  = bi >> 5;                 // 0..15
  const int qt  = (bi < 256) ? (15 - g5) : (g5 - 8);   // heavy/light pairing
  const int tid = threadIdx.x;
  const int w = tid >> 6, lane = tid & 63;
  const int quad = lane >> 4, l16 = lane & 15;

  __shared__ __align__(16) u16 Kb[2][64 * 64];   // also Q staging (16KB)
  __shared__ __align__(16) u16 Vb[2][64 * 64];
  __shared__ __align__(16) u32 Ps[4][2][16 * 32]; // packed bf16x2, per wave

  const int r0    = qt * 128;
  const int nhalf = 2 * qt + 2;            // 64-key halves to process
  const int kcol  = 2048 + kvh * 64;

  const int srow = tid >> 3;               // 0..31
  const int sc   = tid & 7;

  // stage Q (128 rows x 64 d) through Kb; 1024 chunks = 4/thread
  {
    u16* Qb = (u16*)Kb;
#pragma unroll
    for (int i = 0; i < 4; ++i) {
      const int r  = srow + i * 32;
      const int cs = sc ^ (r & 7);
      gload_lds16(qkv + (size_t)(r0 + r) * 3072 + h * 64 + cs * 8,
                  Qb + (size_t)(tid + i * 256) * 8);
    }
  }
  asm volatile("s_waitcnt vmcnt(0)\n\ts_barrier" ::: "memory");

  // hoist Q frags to registers: rows w*32 + g*16 + l16 (row&7 = l16&7)
  const int xm = l16 & 7;                  // swizzle mask for frag reads
  bf16x8 aq[2][2];
  {
    const u16* Qb = (const u16*)Kb;
#pragma unroll
    for (int g = 0; g < 2; ++g) {
      const int qrow = w * 32 + g * 16 + l16;
      aq[g][0] = *(const bf16x8*)&Qb[qrow * 64 + ((quad    ) ^ xm) * 8];
      aq[g][1] = *(const bf16x8*)&Qb[qrow * 64 + ((4 + quad) ^ xm) * 8];
    }
  }
  // Q frag reads complete before K staging overwrites Kb
  asm volatile("s_waitcnt lgkmcnt(0)\n\ts_barrier" ::: "memory");

  auto stageKV = [&](int n) {
    const int k0 = n * 64;
    u16* Kd = Kb[n & 1];
    u16* Vd = Vb[n & 1];
#pragma unroll
    for (int i = 0; i < 2; ++i) {
      const int r  = srow + i * 32;
      const int cs = sc ^ (r & 7);
      gload_lds16(qkv + (size_t)(k0 + r) * 3072 + kcol + cs * 8,
                  Kd + (size_t)(tid + i * 256) * 8);
      gload_lds16(vt + (size_t)(kvh * 64 + r) * 2048 + k0 + cs * 8,
                  Vd + (size_t)(tid + i * 256) * 8);
    }
  };

  stageKV(0);
  asm volatile("s_waitcnt vmcnt(0)\n\ts_barrier" ::: "memory");

  fx4 O[2][4];
  float l_acc[2] = {0.f, 0.f};
#pragma unroll
  for (int g = 0; g < 2; ++g)
#pragma unroll
    for (int c = 0; c < 4; ++c) O[g][c] = fx4{0.f, 0.f, 0.f, 0.f};

  const int s2 = (l16 & 7) << 1;           // Ps pair-chunk swizzle

#pragma unroll 1
  for (int n = 0; n < nhalf; ++n) {
    if (n + 1 < nhalf) stageKV(n + 1);     // async, lands before next barrier
    const u16* Kh = Kb[n & 1];
    const u16* Vd = Vb[n & 1];
    const int k0h = n * 64;

    // QK^T swapped: sc4[g][c][r] = S[key=k0h+c*16+quad*4+r][q=w*32+g*16+l16]
    fx4 sc4[2][4];
    __builtin_amdgcn_s_setprio(1);
#pragma unroll
    for (int c = 0; c < 4; ++c) {
      const int kr = c * 16 + l16;
      const bf16x8 b0 = *(const bf16x8*)&Kh[kr * 64 + ((quad    ) ^ xm) * 8];
      const bf16x8 b1 = *(const bf16x8*)&Kh[kr * 64 + ((4 + quad) ^ xm) * 8];
#pragma unroll
      for (int g = 0; g < 2; ++g) {
        fx4 z = fx4{0.f, 0.f, 0.f, 0.f};
        z         = __builtin_amdgcn_mfma_f32_16x16x32_bf16(b0, aq[g][0], z, 0, 0, 0);
        sc4[g][c] = __builtin_amdgcn_mfma_f32_16x16x32_bf16(b1, aq[g][1], z, 0, 0, 0);
      }
    }
    __builtin_amdgcn_s_setprio(0);

    // p = exp2(s) in-register; mask only when this (wave,group) touches
    // the diagonal (uniform branch).
#pragma unroll
    for (int g = 0; g < 2; ++g) {
      const int qbase = r0 + w * 32 + g * 16;
      const int qg16  = qbase + l16;
      if (k0h + 63 > qbase) {
#pragma unroll
        for (int c = 0; c < 4; ++c)
#pragma unroll
          for (int r = 0; r < 4; ++r) {
            float p = exp2_hw(sc4[g][c][r]);
            if (k0h + c * 16 + quad * 4 + r > qg16) p = 0.f;
            l_acc[g] += p;
            sc4[g][c][r] = p;
          }
      } else {
#pragma unroll
        for (int c = 0; c < 4; ++c)
#pragma unroll
          for (int r = 0; r < 4; ++r) {
            const float p = exp2_hw(sc4[g][c][r]);
            l_acc[g] += p;
            sc4[g][c][r] = p;
          }
      }
      // pack + store: lane(l16,quad) holds keys c*16+quad*4+0..3 of q=l16
#pragma unroll
      for (int c = 0; c < 4; ++c) {
        const u32 lo = cvtpk_bf16(sc4[g][c][0], sc4[g][c][1]);
        const u32 hi = cvtpk_bf16(sc4[g][c][2], sc4[g][c][3]);
        const int c2 = (c * 4 + quad) ^ s2;
        *(uint2*)&Ps[w][g][l16 * 32 + 2 * c2] = uint2{lo, hi};
      }
    }

    // PV: O[g][16q x 64d] += P[g][16q x 64k] * V^T[64d x 64k]
    const bf16x8 ap00 = *(const bf16x8*)&Ps[w][0][l16 * 32 + 2 * ((2 * quad    ) ^ s2)];
    const bf16x8 ap01 = *(const bf16x8*)&Ps[w][0][l16 * 32 + 2 * ((8 + 2 * quad) ^ s2)];
    const bf16x8 ap10 = *(const bf16x8*)&Ps[w][1][l16 * 32 + 2 * ((2 * quad    ) ^ s2)];
    const bf16x8 ap11 = *(const bf16x8*)&Ps[w][1][l16 * 32 + 2 * ((8 + 2 * quad) ^ s2)];
    __builtin_amdgcn_s_setprio(1);
#pragma unroll
    for (int c = 0; c < 4; ++c) {
      const int vr = c * 16 + l16;
      const bf16x8 v0 = *(const bf16x8*)&Vd[vr * 64 + ((quad    ) ^ xm) * 8];
      const bf16x8 v1 = *(const bf16x8*)&Vd[vr * 64 + ((4 + quad) ^ xm) * 8];
      O[0][c] = __builtin_amdgcn_mfma_f32_16x16x32_bf16(ap00, v0, O[0][c], 0, 0, 0);
      O[0][c] = __builtin_amdgcn_mfma_f32_16x16x32_bf16(ap01, v1, O[0][c], 0, 0, 0);
      O[1][c] = __builtin_amdgcn_mfma_f32_16x16x32_bf16(ap10, v0, O[1][c], 0, 0, 0);
      O[1][c] = __builtin_amdgcn_mfma_f32_16x16x32_bf16(ap11, v1, O[1][c], 0, 0, 0);
    }
    __builtin_amdgcn_s_setprio(0);

    // next half's stage landed + all waves done reading this half's bufs
    asm volatile("s_waitcnt vmcnt(0)\n\ts_barrier" ::: "memory");
  }

  // epilogue per group: l(q=l16) butterfly over quads; redistribute inv
#pragma unroll
  for (int g = 0; g < 2; ++g) {
    float l = l_acc[g];
    l += __shfl_xor(l, 16, 64);
    l += __shfl_xor(l, 32, 64);
    const float inv = 1.f / fmaxf(l, 1e-30f);
#pragma unroll
    for (int r = 0; r < 4; ++r) {
      const float iv = __shfl(inv, (lane & 48) | (quad * 4 + r), 64);
      const int qg = r0 + w * 32 + g * 16 + quad * 4 + r;
#pragma unroll
      for (int c = 0; c < 4; ++c)
        attnbuf[(size_t)qg * 2048 + h * 64 + c * 16 + l16] = f2b(O[g][c][r] * iv);
    }
  }
}

// ---------------------------------------------------------------------------
extern "C" void kernel_launch(void* const* d_in, const int* in_sizes, int n_in,
                              void* d_out, int out_size, void* d_ws, size_t ws_size,
                              hipStream_t stream) {
  const float* x    = (const float*)d_in[0];
  const float* Wq   = (const float*)d_in[1];
  const float* Wk   = (const float*)d_in[2];
  const float* Wv   = (const float*)d_in[3];
  const float* Wo   = (const float*)d_in[4];
  const float* cosb = (const float*)d_in[5];
  const float* sinb = (const float*)d_in[6];
  // d_in[7] = attn_mask (causal, applied structurally); d_in[8] = last_pos (=S)
  float* out = (float*)d_out;

  u16* ws      = (u16*)d_ws;
  u16* qkv     = ws;                          // 2048x3072 bf16 (Q scaled+roped, K roped)
  u16* attnbuf = ws + 6291456;                // 2048x2048 bf16
  u16* xb      = ws + 10485760;               // 2048x2048 bf16
  u16* Wqb     = ws + 14680064;               // 2048x2048
  u16* Wkb     = ws + 18874368;               //  512x2048
  u16* Wvb     = ws + 19922944;               //  512x2048
  u16* Wob     = ws + 20971520;               // 2048x2048
  u16* vtg     = ws + 25165824;               //  512x2048 (V^T per kv head)

  // 1) cast inputs to bf16
  cast_kernel<<<7168, 256, 0, stream>>>(x, Wq, Wk, Wv, Wo, xb);

  // 2) QKV projection + fused RoPE/Q-scale + fused V-transpose
  gemm_bt<0><<<dim3(24, 16), 512, 0, stream>>>(
      xb, Wqb, Wkb, Wvb, qkv, 2048, 2048, 2560, 3072, cosb, sinb, vtg);

  // 3) causal MFMA flash attention: 512 blocks (QBLK=128), XCD-localized
  //    kv heads, heavy/light qt pairing per CU
  attn_kernel<<<512, 256, 0, stream>>>(qkv, vtg, attnbuf);

  // 4) output projection (f32 out)
  gemm_bt<1><<<dim3(16, 16), 512, 0, stream>>>(
      attnbuf, Wob, Wob, Wob, out, 2048, 1 << 30, 1 << 30, 2048, cosb, sinb, vtg);
}

// Round 14
// 213.712 us; speedup vs baseline: 1.0211x; 1.0211x over previous
//
#include <hip/hip_runtime.h>
#include <stdint.h>

typedef unsigned short u16;
typedef unsigned int   u32;

typedef __bf16 bf16x8 __attribute__((ext_vector_type(8)));
typedef float  fx4    __attribute__((ext_vector_type(4)));
typedef u16    u16x8  __attribute__((ext_vector_type(8)));
typedef u16    u16x4  __attribute__((ext_vector_type(4)));

typedef __attribute__((address_space(1))) unsigned int as1_u32;
typedef __attribute__((address_space(3))) unsigned int as3_u32;

// async global->LDS, 16B per lane. LDS dest is wave-uniform base + lane*16.
__device__ __forceinline__ void gload_lds16(const void* g, void* lds) {
  __builtin_amdgcn_global_load_lds((const as1_u32*)(uintptr_t)g,
                                   (as3_u32*)(uintptr_t)lds, 16, 0, 0);
}

__device__ __forceinline__ float b2f(u32 bits) {
  union { u32 i; float f; } v; v.i = bits << 16; return v.f;
}
// hardware bf16 convert (RNE; lowers to native cvt on gfx950).
__device__ __forceinline__ u16 f2b_hw(float f) {
  union { __bf16 b; u16 u; } v; v.b = (__bf16)f; return v.u;
}
// raw v_exp_f32: computes 2^x. (__exp2f collides with glibc math.h -- r8.)
__device__ __forceinline__ float exp2_hw(float f) {
  return __builtin_amdgcn_exp2f(f);
}
// packed f32x2 -> bf16x2 convert: dst.lo = cvt(a), dst.hi = cvt(b).
__device__ __forceinline__ u32 cvtpk_bf16(float a, float b) {
  u32 r;
  asm("v_cvt_pk_bf16_f32 %0, %1, %2" : "=v"(r) : "v"(a), "v"(b));
  return r;
}

// ---------------------------------------------------------------------------
// Cast f32 -> bf16 for x, Wq, Wk, Wv, Wo into contiguous ws regions.
// ---------------------------------------------------------------------------
__global__ __launch_bounds__(256) void cast_kernel(
    const float* __restrict__ s0, const float* __restrict__ s1,
    const float* __restrict__ s2, const float* __restrict__ s3,
    const float* __restrict__ s4, u16* __restrict__ dst)
{
  const size_t i8 = ((size_t)blockIdx.x * 256 + threadIdx.x) * 8;
  if (i8 >= 14680064) return;
  const float* src; size_t off;
  if      (i8 <  4194304) { src = s0; off = i8; }
  else if (i8 <  8388608) { src = s1; off = i8 - 4194304; }
  else if (i8 <  9437184) { src = s2; off = i8 - 8388608; }
  else if (i8 < 10485760) { src = s3; off = i8 - 9437184; }
  else                    { src = s4; off = i8 - 10485760; }
  const float4 a = *(const float4*)(src + off);
  const float4 b = *(const float4*)(src + off + 4);
  u16x8 o;
  o[0] = f2b_hw(a.x); o[1] = f2b_hw(a.y); o[2] = f2b_hw(a.z); o[3] = f2b_hw(a.w);
  o[4] = f2b_hw(b.x); o[5] = f2b_hw(b.y); o[6] = f2b_hw(b.z); o[7] = f2b_hw(b.w);
  *(u16x8*)(dst + i8) = o;
}

// ---------------------------------------------------------------------------
// bf16 MFMA GEMM: C[M,N] = A[M,K] * B[N,K]^T, fp32 accum.
// r9/r12-proven config (44 us QKV, conflicts 0; at the measured 2-phase
// structure ceiling ~607 TF, m233): 8 waves / 512 threads, wave-tile 32x64,
// 128x128 block tile, BK=32, 5-buffer 4-ahead async gload_lds pipeline
// (80KB LDS, 2 blk/CU), exact vmcnt ladder 6/4/2/0, LDS XOR swizzle.
// Q pre-scale folds 1/sqrt(D) * log2(e) so attn uses bare v_exp_f32 (=2^x).
// MODE 0: QKV epilogue -- RoPE fused on f32 acc for Q and K; V cols stored
//         TRANSPOSED directly to vt.
// MODE 1: plain f32 store (output projection).
// ---------------------------------------------------------------------------
template <int MODE>
__global__ __launch_bounds__(512) void gemm_bt(
    const u16* __restrict__ A, const u16* __restrict__ B0,
    const u16* __restrict__ B1, const u16* __restrict__ B2,
    void* __restrict__ Cv, int K, int split1, int split2, int ldc,
    const float* __restrict__ cosb, const float* __restrict__ sinb,
    u16* __restrict__ vtg)
{
  __shared__ __align__(16) u16 smem[5 * 8192];   // 5 bufs x (A 8KB + B 8KB)

  const int n0 = blockIdx.x * 128;
  const int m0 = blockIdx.y * 128;

  const u16* Bsel; int nb;
  if (n0 < split1)      { Bsel = B0; nb = n0; }
  else if (n0 < split2) { Bsel = B1; nb = n0 - split1; }
  else                  { Bsel = B2; nb = n0 - split2; }

  const int tid  = threadIdx.x;
  const int wave = tid >> 6, lane = tid & 63;
  const int wm = wave >> 1, wn = wave & 1;     // wave tile: 32 rows x 64 cols
  const int quad = lane >> 4, l16 = lane & 15;

  fx4 acc[2][4];
#pragma unroll
  for (int i = 0; i < 2; ++i)
#pragma unroll
    for (int j = 0; j < 4; ++j) acc[i][j] = fx4{0.f, 0.f, 0.f, 0.f};

  const int row = tid >> 2;            // 0..127: one 16B chunk per thread
  const int ch  = tid & 3;
  const int csw = (ch ^ ((row >> 1) & 3)) * 8;   // pre-swizzled global chunk
  auto stage = [&](int kt, int buf) {
    u16* As = smem + buf * 8192;
    u16* Bs = As + 4096;
    const int k0 = kt * 32;
    gload_lds16(A    + (size_t)(m0 + row) * K + k0 + csw, As + tid * 8);
    gload_lds16(Bsel + (size_t)(nb + row) * K + k0 + csw, Bs + tid * 8);
  };

  const int KT = K >> 5;               // = 64 for all our shapes
  stage(0, 0); stage(1, 1); stage(2, 2); stage(3, 3);
  int bufR = 0, bufW = 4;              // rotating mod-5 buffer counters

  // frag-read swizzle: f(row) = (row>>1)&3 = (l16>>1)&3 (bases = 0 mod 4)
  const int fx = (l16 >> 1) & 3;
  const int cA = (quad ^ fx) * 8;      // swizzled chunk offset (u16 units)

#pragma unroll 1
  for (int kt = 0; kt < KT; ++kt) {
    const int rem = KT - 1 - kt;       // stages newer than kt still issued
    // stage kt complete; up to 3 newer stages (2 loads/thread each) may fly
    if (rem >= 3)      asm volatile("s_waitcnt vmcnt(6)\n\ts_barrier" ::: "memory");
    else if (rem == 2) asm volatile("s_waitcnt vmcnt(4)\n\ts_barrier" ::: "memory");
    else if (rem == 1) asm volatile("s_waitcnt vmcnt(2)\n\ts_barrier" ::: "memory");
    else               asm volatile("s_waitcnt vmcnt(0)\n\ts_barrier" ::: "memory");
    if (kt + 4 < KT) stage(kt + 4, bufW);  // bufW == buf read at kt-1:
                                           // consumed, all waves past barrier

    const u16* As = smem + bufR * 8192;
    const u16* Bs = As + 4096;

    bf16x8 af[2], bfr[4];
#pragma unroll
    for (int t = 0; t < 2; ++t)
      af[t]  = *(const bf16x8*)&As[(wm * 32 + t * 16 + l16) * 32 + cA];
#pragma unroll
    for (int t = 0; t < 4; ++t)
      bfr[t] = *(const bf16x8*)&Bs[(wn * 64 + t * 16 + l16) * 32 + cA];
#pragma unroll
    for (int ti = 0; ti < 2; ++ti)
#pragma unroll
      for (int tj = 0; tj < 4; ++tj)
        acc[ti][tj] = __builtin_amdgcn_mfma_f32_16x16x32_bf16(
            af[ti], bfr[tj], acc[ti][tj], 0, 0, 0);

    bufR = (bufR == 4) ? 0 : bufR + 1;
    bufW = (bufW == 4) ? 0 : bufW + 1;
  }

  if (MODE == 1) {                     // plain f32 store (out-proj)
    float* C = (float*)Cv;
#pragma unroll
    for (int ti = 0; ti < 2; ++ti) {
      const int row_b = m0 + wm * 32 + ti * 16 + quad * 4;
#pragma unroll
      for (int tj = 0; tj < 4; ++tj) {
        const int col = n0 + wn * 64 + tj * 16 + l16;
#pragma unroll
        for (int r = 0; r < 4; ++r)
          C[(size_t)(row_b + r) * ldc + col] = acc[ti][tj][r];
      }
    }
  } else {                             // QKV epilogue
    u16* C = (u16*)Cv;
    const int cb = n0 + wn * 64;       // wave's 64-col span = one head block
    if (cb < 2560) {                   // Q or K: fuse RoPE
      // Q: 2^-3 (1/sqrt(D)) * log2(e) so attn can use v_exp_f32 (=2^x)
      const float qs = (cb < 2048) ? 0.18033688f : 1.0f;
#pragma unroll
      for (int ti = 0; ti < 2; ++ti) {
#pragma unroll
        for (int r = 0; r < 4; ++r) {
          const int s = m0 + wm * 32 + ti * 16 + quad * 4 + r;
          const float* cr = cosb + s * 64;
          const float* sr = sinb + s * 64;
          u16* orow = C + (size_t)s * 3072 + cb;
#pragma unroll
          for (int tj = 0; tj < 2; ++tj) {
            const int d0 = tj * 16 + l16, d1 = d0 + 32;
            const float x0 = acc[ti][tj][r], x1 = acc[ti][tj + 2][r];
            orow[d0] = f2b_hw((x0 * cr[d0] - x1 * sr[d0]) * qs);
            orow[d1] = f2b_hw((x1 * cr[d1] + x0 * sr[d1]) * qs);
          }
        }
      }
    } else {                           // V: store TRANSPOSED to vt[d][key]
      const int vr0 = cb - 2560;
#pragma unroll
      for (int ti = 0; ti < 2; ++ti) {
        const int s0 = m0 + wm * 32 + ti * 16 + quad * 4;
#pragma unroll
        for (int tj = 0; tj < 4; ++tj) {
          const int vr = vr0 + tj * 16 + l16;
          u16x4 o;
#pragma unroll
          for (int r = 0; r < 4; ++r) o[r] = f2b_hw(acc[ti][tj][r]);
          *(u16x4*)(vtg + (size_t)vr * 2048 + s0) = o;
        }
      }
    }
  }
}

// ---------------------------------------------------------------------------
// MFMA causal flash attention (r12-exact revert -- proven 209.9us total).
// r13's QBLK=128 regressed: 512 blocks = 2/CU (occupancy 19->12%), new
// bank conflicts, tail imbalance; TLP loss beat the DS-byte win. Lesson of
// the session: occupancy-reducing amortizations regress, TLP/latency fixes
// win. This is the r12 structure:
//  * swapped-operand QK^T (mfma(K,Q); LDS reads byte-identical, lane holds
//    P[key=c*16+quad*4+r][q=l16]) -> in-register softmax (exp2; log2e
//    folded into Q scale by the gemm).
//  * packed-u32 Ps: v_cvt_pk_bf16_f32 pairs + 4 ds_write_b64 per half
//    (replaced 16 ds_write_u16 + 16 converts); pair-chunk swizzle
//    chunk2 ^= (l16&7)<<1 keeps b64/b128 alignment, conflict-free.
//  * scalar l accumulator; end butterfly shfl_xor(16,32); epilogue pulls
//    inv per O-row via shfl.
//  * KV-head-localized XCD remap (bi&7=kvh -> per-XCD K+V 512KB,
//    L2-resident), 1024 blocks (QBLK=64) = 3 blk/CU (48KB LDS), depth-1
//    double-buffered 64-key halves, async gload_lds staging w/ source
//    pre-swizzle, s_setprio around MFMA clusters.
// Verified MFMA layouts: A/B: m(n)=lane&15, k=quad*8+j; C/D: col=lane&15
// (B-operand index), row=quad*4+reg (A-operand index).
// Ps is per-wave (in-wave DS ordering), no barrier around it.
// ---------------------------------------------------------------------------
__global__ __launch_bounds__(256) void attn_kernel(
    const u16* __restrict__ qkv, const u16* __restrict__ vt,
    u16* __restrict__ attnbuf)
{
  const int bi  = blockIdx.x;
  const int kvh = bi & 7;                  // XCD-local kv head
  const int j   = bi >> 3;                 // 0..127
  const int h   = kvh * 4 + (j & 3);       // head
  const int bx  = 31 - (j >> 2);           // q-tile, heaviest first
  const int tid = threadIdx.x;
  const int w = tid >> 6, lane = tid & 63;
  const int quad = lane >> 4, l16 = lane & 15;

  __shared__ __align__(16) u16 Qs[64 * 64];
  __shared__ __align__(16) u16 Kb[2][64 * 64];
  __shared__ __align__(16) u16 Vb[2][64 * 64];
  __shared__ __align__(16) u32 Ps[4][16 * 32];   // packed bf16x2, per wave

  const int r0    = bx * 64;
  const int nhalf = bx + 1;                // 64-key halves to process
  const int kcol  = 2048 + kvh * 64;

  const int srow = tid >> 3;               // 0..31 (i=1 adds 32)
  const int sc   = tid & 7;

  auto stageQ = [&]() {
#pragma unroll
    for (int i = 0; i < 2; ++i) {
      const int r  = srow + i * 32;
      const int cs = sc ^ (r & 7);
      gload_lds16(qkv + (size_t)(r0 + r) * 3072 + h * 64 + cs * 8,
                  Qs + (size_t)(tid + i * 256) * 8);
    }
  };
  auto stageKV = [&](int n) {
    const int k0 = n * 64;
    u16* Kd = Kb[n & 1];
    u16* Vd = Vb[n & 1];
#pragma unroll
    for (int i = 0; i < 2; ++i) {
      const int r  = srow + i * 32;
      const int cs = sc ^ (r & 7);
      gload_lds16(qkv + (size_t)(k0 + r) * 3072 + kcol + cs * 8,
                  Kd + (size_t)(tid + i * 256) * 8);
      gload_lds16(vt + (size_t)(kvh * 64 + r) * 2048 + k0 + cs * 8,
                  Vd + (size_t)(tid + i * 256) * 8);
    }
  };

  stageQ();
  stageKV(0);
  asm volatile("s_waitcnt vmcnt(0)\n\ts_barrier" ::: "memory");

  // Q fragments hoisted out of the tile loop (row = w*16+l16, row&7 = l16&7)
  const int xm = l16 & 7;                  // swizzle mask for frag reads
  const int qrow = w * 16 + l16;
  const bf16x8 aq0 = *(const bf16x8*)&Qs[qrow * 64 + ((quad    ) ^ xm) * 8];
  const bf16x8 aq1 = *(const bf16x8*)&Qs[qrow * 64 + ((4 + quad) ^ xm) * 8];

  fx4 O[4];
  float l_acc = 0.f;
#pragma unroll
  for (int c = 0; c < 4; ++c) O[c] = fx4{0.f, 0.f, 0.f, 0.f};

  const int s2 = (l16 & 7) << 1;           // Ps pair-chunk swizzle

#pragma unroll 1
  for (int n = 0; n < nhalf; ++n) {
    if (n + 1 < nhalf) stageKV(n + 1);     // async, lands before next barrier
    const u16* Kh = Kb[n & 1];
    const u16* Vd = Vb[n & 1];
    const int k0h = n * 64;

    // QK^T swapped: sc4[c][r] = S[key = k0h + c*16 + quad*4 + r][q = l16]
    fx4 sc4[4];
    __builtin_amdgcn_s_setprio(1);
#pragma unroll
    for (int c = 0; c < 4; ++c) {
      const int kr = c * 16 + l16;
      const bf16x8 b0 = *(const bf16x8*)&Kh[kr * 64 + ((quad    ) ^ xm) * 8];
      const bf16x8 b1 = *(const bf16x8*)&Kh[kr * 64 + ((4 + quad) ^ xm) * 8];
      fx4 z = fx4{0.f, 0.f, 0.f, 0.f};
      z      = __builtin_amdgcn_mfma_f32_16x16x32_bf16(b0, aq0, z, 0, 0, 0);
      sc4[c] = __builtin_amdgcn_mfma_f32_16x16x32_bf16(b1, aq1, z, 0, 0, 0);
    }
    __builtin_amdgcn_s_setprio(0);

    // p = exp2(s) in-register; causal mask only on the diagonal half.
    const int qg16 = r0 + w * 16 + l16;    // this lane's q
    if (k0h >= r0) {
#pragma unroll
      for (int c = 0; c < 4; ++c)
#pragma unroll
        for (int r = 0; r < 4; ++r) {
          float p = exp2_hw(sc4[c][r]);
          if (k0h + c * 16 + quad * 4 + r > qg16) p = 0.f;
          l_acc += p;
          sc4[c][r] = p;
        }
    } else {
#pragma unroll
      for (int c = 0; c < 4; ++c)
#pragma unroll
        for (int r = 0; r < 4; ++r) {
          const float p = exp2_hw(sc4[c][r]);
          l_acc += p;
          sc4[c][r] = p;
        }
    }

    // pack + store: lane(l16,quad) holds keys c*16+quad*4+0..3 of q=l16.
    // u32 pair-chunk chunk2 = c*4+quad, swizzled ^s2 (even -> b64/b128 ok).
#pragma unroll
    for (int c = 0; c < 4; ++c) {
      const u32 lo = cvtpk_bf16(sc4[c][0], sc4[c][1]);
      const u32 hi = cvtpk_bf16(sc4[c][2], sc4[c][3]);
      const int c2 = (c * 4 + quad) ^ s2;
      *(uint2*)&Ps[w][l16 * 32 + 2 * c2] = uint2{lo, hi};
    }

    // PV: O[16q x 64d] += P[16q x 64k] * V^T[64d x 64k]
    // A-frag: m=q=lane&15 (row l16), k=keys quad*8+j -> logical chunk2
    // {2quad, 2quad+1} (ap0), {8+2quad, ...} (ap1), phys = ^s2.
    const bf16x8 ap0 = *(const bf16x8*)&Ps[w][l16 * 32 + 2 * ((2 * quad    ) ^ s2)];
    const bf16x8 ap1 = *(const bf16x8*)&Ps[w][l16 * 32 + 2 * ((8 + 2 * quad) ^ s2)];
    __builtin_amdgcn_s_setprio(1);
#pragma unroll
    for (int c = 0; c < 4; ++c) {
      const int vr = c * 16 + l16;
      const bf16x8 v0 = *(const bf16x8*)&Vd[vr * 64 + ((quad    ) ^ xm) * 8];
      const bf16x8 v1 = *(const bf16x8*)&Vd[vr * 64 + ((4 + quad) ^ xm) * 8];
      O[c] = __builtin_amdgcn_mfma_f32_16x16x32_bf16(ap0, v0, O[c], 0, 0, 0);
      O[c] = __builtin_amdgcn_mfma_f32_16x16x32_bf16(ap1, v1, O[c], 0, 0, 0);
    }
    __builtin_amdgcn_s_setprio(0);

    // next half's stage landed + all waves done reading this half's bufs
    asm volatile("s_waitcnt vmcnt(0)\n\ts_barrier" ::: "memory");
  }

  // epilogue: l(q=l16) = butterfly over quads; redistribute inv to O rows
  float l = l_acc;
  l += __shfl_xor(l, 16, 64);
  l += __shfl_xor(l, 32, 64);
  const float inv = 1.f / fmaxf(l, 1e-30f);
#pragma unroll
  for (int r = 0; r < 4; ++r) {
    const float iv = __shfl(inv, (lane & 48) | (quad * 4 + r), 64);
    const int qg = r0 + w * 16 + quad * 4 + r;
#pragma unroll
    for (int c = 0; c < 4; ++c)
      attnbuf[(size_t)qg * 2048 + h * 64 + c * 16 + l16] = f2b_hw(O[c][r] * iv);
  }
}

// ---------------------------------------------------------------------------
extern "C" void kernel_launch(void* const* d_in, const int* in_sizes, int n_in,
                              void* d_out, int out_size, void* d_ws, size_t ws_size,
                              hipStream_t stream) {
  const float* x    = (const float*)d_in[0];
  const float* Wq   = (const float*)d_in[1];
  const float* Wk   = (const float*)d_in[2];
  const float* Wv   = (const float*)d_in[3];
  const float* Wo   = (const float*)d_in[4];
  const float* cosb = (const float*)d_in[5];
  const float* sinb = (const float*)d_in[6];
  // d_in[7] = attn_mask (causal, applied structurally); d_in[8] = last_pos (=S)
  float* out = (float*)d_out;

  u16* ws      = (u16*)d_ws;
  u16* qkv     = ws;                          // 2048x3072 bf16 (Q scaled+roped, K roped)
  u16* attnbuf = ws + 6291456;                // 2048x2048 bf16
  u16* xb      = ws + 10485760;               // 2048x2048 bf16
  u16* Wqb     = ws + 14680064;               // 2048x2048
  u16* Wkb     = ws + 18874368;               //  512x2048
  u16* Wvb     = ws + 19922944;               //  512x2048
  u16* Wob     = ws + 20971520;               // 2048x2048
  u16* vtg     = ws + 25165824;               //  512x2048 (V^T per kv head)

  // 1) cast inputs to bf16
  cast_kernel<<<7168, 256, 0, stream>>>(x, Wq, Wk, Wv, Wo, xb);

  // 2) QKV projection + fused RoPE/Q-scale + fused V-transpose
  gemm_bt<0><<<dim3(24, 16), 512, 0, stream>>>(
      xb, Wqb, Wkb, Wvb, qkv, 2048, 2048, 2560, 3072, cosb, sinb, vtg);

  // 3) causal MFMA flash attention: 1024 blocks, XCD-localized kv heads
  attn_kernel<<<1024, 256, 0, stream>>>(qkv, vtg, attnbuf);

  // 4) output projection (f32 out)
  gemm_bt<1><<<dim3(16, 16), 512, 0, stream>>>(
      attnbuf, Wob, Wob, Wob, out, 2048, 1 << 30, 1 << 30, 2048, cosb, sinb, vtg);
}

// Round 16
// 213.048 us; speedup vs baseline: 1.0243x; 1.0031x over previous
//
#include <hip/hip_runtime.h>
#include <stdint.h>

typedef unsigned short u16;
typedef unsigned int   u32;

typedef __bf16 bf16x8 __attribute__((ext_vector_type(8)));
typedef float  fx4    __attribute__((ext_vector_type(4)));
typedef u16    u16x8  __attribute__((ext_vector_type(8)));
typedef u16    u16x4  __attribute__((ext_vector_type(4)));

typedef __attribute__((address_space(1))) unsigned int as1_u32;
typedef __attribute__((address_space(3))) unsigned int as3_u32;

// async global->LDS, 16B per lane. LDS dest is wave-uniform base + lane*16.
__device__ __forceinline__ void gload_lds16(const void* g, void* lds) {
  __builtin_amdgcn_global_load_lds((const as1_u32*)(uintptr_t)g,
                                   (as3_u32*)(uintptr_t)lds, 16, 0, 0);
}

__device__ __forceinline__ float b2f(u32 bits) {
  union { u32 i; float f; } v; v.i = bits << 16; return v.f;
}
// hardware bf16 convert (RNE; lowers to native cvt on gfx950).
__device__ __forceinline__ u16 f2b_hw(float f) {
  union { __bf16 b; u16 u; } v; v.b = (__bf16)f; return v.u;
}
// raw v_exp_f32: computes 2^x. (__exp2f collides with glibc math.h -- r8.)
__device__ __forceinline__ float exp2_hw(float f) {
  return __builtin_amdgcn_exp2f(f);
}
// packed f32x2 -> bf16x2 convert: dst.lo = cvt(a), dst.hi = cvt(b).
__device__ __forceinline__ u32 cvtpk_bf16(float a, float b) {
  u32 r;
  asm("v_cvt_pk_bf16_f32 %0, %1, %2" : "=v"(r) : "v"(a), "v"(b));
  return r;
}

// ---------------------------------------------------------------------------
// Cast f32 -> bf16 for x, Wq, Wk, Wv, Wo into contiguous ws regions.
// ---------------------------------------------------------------------------
__global__ __launch_bounds__(256) void cast_kernel(
    const float* __restrict__ s0, const float* __restrict__ s1,
    const float* __restrict__ s2, const float* __restrict__ s3,
    const float* __restrict__ s4, u16* __restrict__ dst)
{
  const size_t i8 = ((size_t)blockIdx.x * 256 + threadIdx.x) * 8;
  if (i8 >= 14680064) return;
  const float* src; size_t off;
  if      (i8 <  4194304) { src = s0; off = i8; }
  else if (i8 <  8388608) { src = s1; off = i8 - 4194304; }
  else if (i8 <  9437184) { src = s2; off = i8 - 8388608; }
  else if (i8 < 10485760) { src = s3; off = i8 - 9437184; }
  else                    { src = s4; off = i8 - 10485760; }
  const float4 a = *(const float4*)(src + off);
  const float4 b = *(const float4*)(src + off + 4);
  u16x8 o;
  o[0] = f2b_hw(a.x); o[1] = f2b_hw(a.y); o[2] = f2b_hw(a.z); o[3] = f2b_hw(a.w);
  o[4] = f2b_hw(b.x); o[5] = f2b_hw(b.y); o[6] = f2b_hw(b.z); o[7] = f2b_hw(b.w);
  *(u16x8*)(dst + i8) = o;
}

// ---------------------------------------------------------------------------
// bf16 MFMA GEMM: C[M,N] = A[M,K] * B[N,K]^T, fp32 accum.
// r9/r12-proven config (44-45 us QKV, conflicts 0; at the measured 2-phase
// structure ceiling, m233): 8 waves / 512 threads, wave-tile 32x64,
// 128x128 block tile, BK=32, 5-buffer 4-ahead async gload_lds pipeline
// (80KB LDS, 2 blk/CU), exact vmcnt ladder 6/4/2/0, LDS XOR swizzle.
// Q pre-scale folds 1/sqrt(D) * log2(e) so attn uses bare v_exp_f32 (=2^x).
// MODE 0: QKV epilogue -- RoPE fused on f32 acc for Q and K; V cols stored
//         TRANSPOSED directly to vt.
// MODE 1: plain f32 store (output projection).
// ---------------------------------------------------------------------------
template <int MODE>
__global__ __launch_bounds__(512) void gemm_bt(
    const u16* __restrict__ A, const u16* __restrict__ B0,
    const u16* __restrict__ B1, const u16* __restrict__ B2,
    void* __restrict__ Cv, int K, int split1, int split2, int ldc,
    const float* __restrict__ cosb, const float* __restrict__ sinb,
    u16* __restrict__ vtg)
{
  __shared__ __align__(16) u16 smem[5 * 8192];   // 5 bufs x (A 8KB + B 8KB)

  const int n0 = blockIdx.x * 128;
  const int m0 = blockIdx.y * 128;

  const u16* Bsel; int nb;
  if (n0 < split1)      { Bsel = B0; nb = n0; }
  else if (n0 < split2) { Bsel = B1; nb = n0 - split1; }
  else                  { Bsel = B2; nb = n0 - split2; }

  const int tid  = threadIdx.x;
  const int wave = tid >> 6, lane = tid & 63;
  const int wm = wave >> 1, wn = wave & 1;     // wave tile: 32 rows x 64 cols
  const int quad = lane >> 4, l16 = lane & 15;

  fx4 acc[2][4];
#pragma unroll
  for (int i = 0; i < 2; ++i)
#pragma unroll
    for (int j = 0; j < 4; ++j) acc[i][j] = fx4{0.f, 0.f, 0.f, 0.f};

  const int row = tid >> 2;            // 0..127: one 16B chunk per thread
  const int ch  = tid & 3;
  const int csw = (ch ^ ((row >> 1) & 3)) * 8;   // pre-swizzled global chunk
  auto stage = [&](int kt, int buf) {
    u16* As = smem + buf * 8192;
    u16* Bs = As + 4096;
    const int k0 = kt * 32;
    gload_lds16(A    + (size_t)(m0 + row) * K + k0 + csw, As + tid * 8);
    gload_lds16(Bsel + (size_t)(nb + row) * K + k0 + csw, Bs + tid * 8);
  };

  const int KT = K >> 5;               // = 64 for all our shapes
  stage(0, 0); stage(1, 1); stage(2, 2); stage(3, 3);
  int bufR = 0, bufW = 4;              // rotating mod-5 buffer counters

  // frag-read swizzle: f(row) = (row>>1)&3 = (l16>>1)&3 (bases = 0 mod 4)
  const int fx = (l16 >> 1) & 3;
  const int cA = (quad ^ fx) * 8;      // swizzled chunk offset (u16 units)

#pragma unroll 1
  for (int kt = 0; kt < KT; ++kt) {
    const int rem = KT - 1 - kt;       // stages newer than kt still issued
    // stage kt complete; up to 3 newer stages (2 loads/thread each) may fly
    if (rem >= 3)      asm volatile("s_waitcnt vmcnt(6)\n\ts_barrier" ::: "memory");
    else if (rem == 2) asm volatile("s_waitcnt vmcnt(4)\n\ts_barrier" ::: "memory");
    else if (rem == 1) asm volatile("s_waitcnt vmcnt(2)\n\ts_barrier" ::: "memory");
    else               asm volatile("s_waitcnt vmcnt(0)\n\ts_barrier" ::: "memory");
    if (kt + 4 < KT) stage(kt + 4, bufW);  // bufW == buf read at kt-1:
                                           // consumed, all waves past barrier

    const u16* As = smem + bufR * 8192;
    const u16* Bs = As + 4096;

    bf16x8 af[2], bfr[4];
#pragma unroll
    for (int t = 0; t < 2; ++t)
      af[t]  = *(const bf16x8*)&As[(wm * 32 + t * 16 + l16) * 32 + cA];
#pragma unroll
    for (int t = 0; t < 4; ++t)
      bfr[t] = *(const bf16x8*)&Bs[(wn * 64 + t * 16 + l16) * 32 + cA];
#pragma unroll
    for (int ti = 0; ti < 2; ++ti)
#pragma unroll
      for (int tj = 0; tj < 4; ++tj)
        acc[ti][tj] = __builtin_amdgcn_mfma_f32_16x16x32_bf16(
            af[ti], bfr[tj], acc[ti][tj], 0, 0, 0);

    bufR = (bufR == 4) ? 0 : bufR + 1;
    bufW = (bufW == 4) ? 0 : bufW + 1;
  }

  if (MODE == 1) {                     // plain f32 store (out-proj)
    float* C = (float*)Cv;
#pragma unroll
    for (int ti = 0; ti < 2; ++ti) {
      const int row_b = m0 + wm * 32 + ti * 16 + quad * 4;
#pragma unroll
      for (int tj = 0; tj < 4; ++tj) {
        const int col = n0 + wn * 64 + tj * 16 + l16;
#pragma unroll
        for (int r = 0; r < 4; ++r)
          C[(size_t)(row_b + r) * ldc + col] = acc[ti][tj][r];
      }
    }
  } else {                             // QKV epilogue
    u16* C = (u16*)Cv;
    const int cb = n0 + wn * 64;       // wave's 64-col span = one head block
    if (cb < 2560) {                   // Q or K: fuse RoPE
      // Q: 2^-3 (1/sqrt(D)) * log2(e) so attn can use v_exp_f32 (=2^x)
      const float qs = (cb < 2048) ? 0.18033688f : 1.0f;
#pragma unroll
      for (int ti = 0; ti < 2; ++ti) {
#pragma unroll
        for (int r = 0; r < 4; ++r) {
          const int s = m0 + wm * 32 + ti * 16 + quad * 4 + r;
          const float* cr = cosb + s * 64;
          const float* sr = sinb + s * 64;
          u16* orow = C + (size_t)s * 3072 + cb;
#pragma unroll
          for (int tj = 0; tj < 2; ++tj) {
            const int d0 = tj * 16 + l16, d1 = d0 + 32;
            const float x0 = acc[ti][tj][r], x1 = acc[ti][tj + 2][r];
            orow[d0] = f2b_hw((x0 * cr[d0] - x1 * sr[d0]) * qs);
            orow[d1] = f2b_hw((x1 * cr[d1] + x0 * sr[d1]) * qs);
          }
        }
      }
    } else {                           // V: store TRANSPOSED to vt[d][key]
      const int vr0 = cb - 2560;
#pragma unroll
      for (int ti = 0; ti < 2; ++ti) {
        const int s0 = m0 + wm * 32 + ti * 16 + quad * 4;
#pragma unroll
        for (int tj = 0; tj < 4; ++tj) {
          const int vr = vr0 + tj * 16 + l16;
          u16x4 o;
#pragma unroll
          for (int r = 0; r < 4; ++r) o[r] = f2b_hw(acc[ti][tj][r]);
          *(u16x4*)(vtg + (size_t)vr * 2048 + s0) = o;
        }
      }
    }
  }
}

// ---------------------------------------------------------------------------
// MFMA causal flash attention (r12 structure + Q-direct-load; resubmit of
// r15 -- round-15 bench was an infra container failure, no kernel signal;
// code audited: no OOB, no new sync, no hang mechanism).
// Q fragments loaded DIRECTLY global->register (2 coalesced
// global_load_dwordx4/lane, one-time, L2/L3-hot -- qkv was just written by
// gemm0; logical layout, no swizzle needed). Frees the 8KB Qs buffer:
// LDS 48KB -> 40KB => 4 blocks/CU (was 3) at grid 1024 = exactly 4/CU.
// +33% waves/SIMD for the depth-1 prefetch to hide under; Q-stage barrier
// pair deleted. Session pattern: TLP fixes win, amortization loses.
// r12 structure otherwise:
//  * swapped-operand QK^T (mfma(K,Q); lane holds P[key=c*16+quad*4+r][q=l16])
//    -> in-register softmax (exp2; log2e folded into Q scale by the gemm).
//  * packed-u32 Ps: v_cvt_pk_bf16_f32 pairs + 4 ds_write_b64 per half;
//    pair-chunk swizzle chunk2 ^= (l16&7)<<1 (b64/b128-aligned, conflict-free).
//  * scalar l accumulator; butterfly shfl_xor(16,32); inv via shfl.
//  * KV-head-localized XCD remap (bi&7=kvh -> per-XCD K+V 512KB L2-resident),
//    QBLK=64, depth-1 double-buffered 64-key halves, async gload_lds staging
//    w/ source pre-swizzle, s_setprio around MFMA clusters.
// Verified MFMA layouts: A/B: m(n)=lane&15, k=quad*8+j; C/D: col=lane&15
// (B-operand index), row=quad*4+reg (A-operand index).
// Ps is per-wave (in-wave DS ordering), no barrier around it.
// ---------------------------------------------------------------------------
__global__ __launch_bounds__(256) void attn_kernel(
    const u16* __restrict__ qkv, const u16* __restrict__ vt,
    u16* __restrict__ attnbuf)
{
  const int bi  = blockIdx.x;
  const int kvh = bi & 7;                  // XCD-local kv head
  const int j   = bi >> 3;                 // 0..127
  const int h   = kvh * 4 + (j & 3);       // head
  const int bx  = 31 - (j >> 2);           // q-tile, heaviest first
  const int tid = threadIdx.x;
  const int w = tid >> 6, lane = tid & 63;
  const int quad = lane >> 4, l16 = lane & 15;

  __shared__ __align__(16) u16 Kb[2][64 * 64];
  __shared__ __align__(16) u16 Vb[2][64 * 64];
  __shared__ __align__(16) u32 Ps[4][16 * 32];   // packed bf16x2, per wave

  const int r0    = bx * 64;
  const int nhalf = bx + 1;                // 64-key halves to process
  const int kcol  = 2048 + kvh * 64;

  const int srow = tid >> 3;               // 0..31 (i=1 adds 32)
  const int sc   = tid & 7;

  // Q fragments DIRECT from global (one-time; rows r0 + w*16 + l16).
  // aq0 covers k=quad*8+j (elems quad*8..+7), aq1 covers k=32+quad*8+j.
  const u16* qrowp = qkv + (size_t)(r0 + w * 16 + l16) * 3072 + h * 64;
  const bf16x8 aq0 = *(const bf16x8*)(qrowp + quad * 8);
  const bf16x8 aq1 = *(const bf16x8*)(qrowp + 32 + quad * 8);

  auto stageKV = [&](int n) {
    const int k0 = n * 64;
    u16* Kd = Kb[n & 1];
    u16* Vd = Vb[n & 1];
#pragma unroll
    for (int i = 0; i < 2; ++i) {
      const int r  = srow + i * 32;
      const int cs = sc ^ (r & 7);
      gload_lds16(qkv + (size_t)(k0 + r) * 3072 + kcol + cs * 8,
                  Kd + (size_t)(tid + i * 256) * 8);
      gload_lds16(vt + (size_t)(kvh * 64 + r) * 2048 + k0 + cs * 8,
                  Vd + (size_t)(tid + i * 256) * 8);
    }
  };

  stageKV(0);
  asm volatile("s_waitcnt vmcnt(0)\n\ts_barrier" ::: "memory");

  const int xm = l16 & 7;                  // swizzle mask for K/V frag reads

  fx4 O[4];
  float l_acc = 0.f;
#pragma unroll
  for (int c = 0; c < 4; ++c) O[c] = fx4{0.f, 0.f, 0.f, 0.f};

  const int s2 = (l16 & 7) << 1;           // Ps pair-chunk swizzle

#pragma unroll 1
  for (int n = 0; n < nhalf; ++n) {
    if (n + 1 < nhalf) stageKV(n + 1);     // async, lands before next barrier
    const u16* Kh = Kb[n & 1];
    const u16* Vd = Vb[n & 1];
    const int k0h = n * 64;

    // QK^T swapped: sc4[c][r] = S[key = k0h + c*16 + quad*4 + r][q = l16]
    fx4 sc4[4];
    __builtin_amdgcn_s_setprio(1);
#pragma unroll
    for (int c = 0; c < 4; ++c) {
      const int kr = c * 16 + l16;
      const bf16x8 b0 = *(const bf16x8*)&Kh[kr * 64 + ((quad    ) ^ xm) * 8];
      const bf16x8 b1 = *(const bf16x8*)&Kh[kr * 64 + ((4 + quad) ^ xm) * 8];
      fx4 z = fx4{0.f, 0.f, 0.f, 0.f};
      z      = __builtin_amdgcn_mfma_f32_16x16x32_bf16(b0, aq0, z, 0, 0, 0);
      sc4[c] = __builtin_amdgcn_mfma_f32_16x16x32_bf16(b1, aq1, z, 0, 0, 0);
    }
    __builtin_amdgcn_s_setprio(0);

    // p = exp2(s) in-register; causal mask only on the diagonal half.
    const int qg16 = r0 + w * 16 + l16;    // this lane's q
    if (k0h >= r0) {
#pragma unroll
      for (int c = 0; c < 4; ++c)
#pragma unroll
        for (int r = 0; r < 4; ++r) {
          float p = exp2_hw(sc4[c][r]);
          if (k0h + c * 16 + quad * 4 + r > qg16) p = 0.f;
          l_acc += p;
          sc4[c][r] = p;
        }
    } else {
#pragma unroll
      for (int c = 0; c < 4; ++c)
#pragma unroll
        for (int r = 0; r < 4; ++r) {
          const float p = exp2_hw(sc4[c][r]);
          l_acc += p;
          sc4[c][r] = p;
        }
    }

    // pack + store: lane(l16,quad) holds keys c*16+quad*4+0..3 of q=l16.
    // u32 pair-chunk chunk2 = c*4+quad, swizzled ^s2 (even -> b64/b128 ok).
#pragma unroll
    for (int c = 0; c < 4; ++c) {
      const u32 lo = cvtpk_bf16(sc4[c][0], sc4[c][1]);
      const u32 hi = cvtpk_bf16(sc4[c][2], sc4[c][3]);
      const int c2 = (c * 4 + quad) ^ s2;
      *(uint2*)&Ps[w][l16 * 32 + 2 * c2] = uint2{lo, hi};
    }

    // PV: O[16q x 64d] += P[16q x 64k] * V^T[64d x 64k]
    // A-frag: m=q=lane&15 (row l16), k=keys quad*8+j -> logical chunk2
    // {2quad, 2quad+1} (ap0), {8+2quad, ...} (ap1), phys = ^s2.
    const bf16x8 ap0 = *(const bf16x8*)&Ps[w][l16 * 32 + 2 * ((2 * quad    ) ^ s2)];
    const bf16x8 ap1 = *(const bf16x8*)&Ps[w][l16 * 32 + 2 * ((8 + 2 * quad) ^ s2)];
    __builtin_amdgcn_s_setprio(1);
#pragma unroll
    for (int c = 0; c < 4; ++c) {
      const int vr = c * 16 + l16;
      const bf16x8 v0 = *(const bf16x8*)&Vd[vr * 64 + ((quad    ) ^ xm) * 8];
      const bf16x8 v1 = *(const bf16x8*)&Vd[vr * 64 + ((4 + quad) ^ xm) * 8];
      O[c] = __builtin_amdgcn_mfma_f32_16x16x32_bf16(ap0, v0, O[c], 0, 0, 0);
      O[c] = __builtin_amdgcn_mfma_f32_16x16x32_bf16(ap1, v1, O[c], 0, 0, 0);
    }
    __builtin_amdgcn_s_setprio(0);

    // next half's stage landed + all waves done reading this half's bufs
    asm volatile("s_waitcnt vmcnt(0)\n\ts_barrier" ::: "memory");
  }

  // epilogue: l(q=l16) = butterfly over quads; redistribute inv to O rows
  float l = l_acc;
  l += __shfl_xor(l, 16, 64);
  l += __shfl_xor(l, 32, 64);
  const float inv = 1.f / fmaxf(l, 1e-30f);
#pragma unroll
  for (int r = 0; r < 4; ++r) {
    const float iv = __shfl(inv, (lane & 48) | (quad * 4 + r), 64);
    const int qg = r0 + w * 16 + quad * 4 + r;
#pragma unroll
    for (int c = 0; c < 4; ++c)
      attnbuf[(size_t)qg * 2048 + h * 64 + c * 16 + l16] = f2b_hw(O[c][r] * iv);
  }
}

// ---------------------------------------------------------------------------
extern "C" void kernel_launch(void* const* d_in, const int* in_sizes, int n_in,
                              void* d_out, int out_size, void* d_ws, size_t ws_size,
                              hipStream_t stream) {
  const float* x    = (const float*)d_in[0];
  const float* Wq   = (const float*)d_in[1];
  const float* Wk   = (const float*)d_in[2];
  const float* Wv   = (const float*)d_in[3];
  const float* Wo   = (const float*)d_in[4];
  const float* cosb = (const float*)d_in[5];
  const float* sinb = (const float*)d_in[6];
  // d_in[7] = attn_mask (causal, applied structurally); d_in[8] = last_pos (=S)
  float* out = (float*)d_out;

  u16* ws      = (u16*)d_ws;
  u16* qkv     = ws;                          // 2048x3072 bf16 (Q scaled+roped, K roped)
  u16* attnbuf = ws + 6291456;                // 2048x2048 bf16
  u16* xb      = ws + 10485760;               // 2048x2048 bf16
  u16* Wqb     = ws + 14680064;               // 2048x2048
  u16* Wkb     = ws + 18874368;               //  512x2048
  u16* Wvb     = ws + 19922944;               //  512x2048
  u16* Wob     = ws + 20971520;               // 2048x2048
  u16* vtg     = ws + 25165824;               //  512x2048 (V^T per kv head)

  // 1) cast inputs to bf16
  cast_kernel<<<7168, 256, 0, stream>>>(x, Wq, Wk, Wv, Wo, xb);

  // 2) QKV projection + fused RoPE/Q-scale + fused V-transpose
  gemm_bt<0><<<dim3(24, 16), 512, 0, stream>>>(
      xb, Wqb, Wkb, Wvb, qkv, 2048, 2048, 2560, 3072, cosb, sinb, vtg);

  // 3) causal MFMA flash attention: 1024 blocks (4/CU), XCD-localized kv heads
  attn_kernel<<<1024, 256, 0, stream>>>(qkv, vtg, attnbuf);

  // 4) output projection (f32 out)
  gemm_bt<1><<<dim3(16, 16), 512, 0, stream>>>(
      attnbuf, Wob, Wob, Wob, out, 2048, 1 << 30, 1 << 30, 2048, cosb, sinb, vtg);
}